// Round 3
// baseline (58.313 us; speedup 1.0000x reference)
//
#include <hip/hip_runtime.h>

// Problem constants (from reference):
//   B=16, H=32, W=32, C=16, KH=KW=3, F=32, HO=WO=30, K=144 (+1 bias row)
// out[b,k,ho,wo,f]:
//   k < 144: k = kh*48 + kw*16 + c  ->  x[b, ho+kh, wo+kw, c] * w[k,f]
//   k == 144:                            1.0 * w[144,f]
// Output: (16,145,30,30,32) fp32, contiguous, 267 MB -> write-BW bound.
// Strategy: one block per (b,k). All k-dependent decode is block-uniform,
// w float4 loaded once per thread (f4 invariant across loop since 256%8==0),
// inner loop = one div-by-30 + one L1-hot x load + 4 muls + 1 NT float4 store.

#define BB   16
#define HH   32
#define WW   32
#define CC   16
#define FF   32
#define KP1  145
#define LL   900            // HO*WO
#define ROW4 (LL * FF / 4)  // float4s per (b,k) row = 7200

typedef float f32x4 __attribute__((ext_vector_type(4)));

__global__ __launch_bounds__(256) void vinput_conv_kernel(
    const float* __restrict__ x,      // (B,H,W,C)
    const float* __restrict__ w,      // (K+1,1,F)
    float* __restrict__ out)          // (B,K+1,HO,WO,F)
{
    const unsigned bid = blockIdx.x;          // 0..2319 = b*145 + k
    const unsigned b   = bid / KP1;
    const unsigned k   = bid - b * KP1;

    const unsigned tid = threadIdx.x;
    const unsigned f4  = tid & 7;             // invariant across the loop (256 % 8 == 0)

    // w float4 for this lane's f-slot: loaded once.
    const f32x4 wv = *reinterpret_cast<const f32x4*>(w + k * FF + f4 * 4);

    f32x4* __restrict__ out4 = reinterpret_cast<f32x4*>(out) + (size_t)bid * ROW4;

    if (k == 144) {
        // bias row: g = 1.0, pure streaming store of the w row
        for (unsigned u = tid; u < ROW4; u += 256) {
            __builtin_nontemporal_store(wv, out4 + u);
        }
    } else {
        const unsigned kh = k / 48;           // k = kh*48 + kw*16 + c (block-uniform)
        const unsigned r  = k - kh * 48;
        const unsigned kw = r >> 4;
        const unsigned c  = r & 15;
        const float* __restrict__ xbase =
            x + ((b * HH + kh) * WW + kw) * CC + c;   // + ho*512 + wo*16

        for (unsigned u = tid; u < ROW4; u += 256) {
            const unsigned l  = u >> 3;
            const unsigned ho = l / 30;       // magic-mul
            const unsigned wo = l - ho * 30;
            const float g = xbase[ho * (WW * CC) + wo * CC];
            f32x4 o = g * wv;                 // vector-scalar mul on ext_vector
            __builtin_nontemporal_store(o, out4 + u);
        }
    }
}

extern "C" void kernel_launch(void* const* d_in, const int* in_sizes, int n_in,
                              void* d_out, int out_size, void* d_ws, size_t ws_size,
                              hipStream_t stream) {
    const float* x = (const float*)d_in[0];   // (16,32,32,16) fp32
    const float* w = (const float*)d_in[1];   // (145,1,32) fp32
    float* out = (float*)d_out;               // (16,145,30,30,32) fp32

    const int grid = BB * KP1;                // 2320 blocks, one per (b,k)
    vinput_conv_kernel<<<grid, 256, 0, stream>>>(x, w, out);
}

// Round 4
// 46.755 us; speedup vs baseline: 1.2472x; 1.2472x over previous
//
#include <hip/hip_runtime.h>

// Problem constants (from reference):
//   B=16, H=32, W=32, C=16, KH=KW=3, F=32, HO=WO=30, K=144 (+1 bias row)
// out[b,k,ho,wo,f]:
//   k < 144: k = kh*48 + kw*16 + c  ->  x[b, ho+kh, wo+kw, c] * w[k,f]
//   k == 144:                            1.0 * w[144,f]
// Output: (16,145,30,30,32) fp32, contiguous, 267 MB -> write-BW bound.
// Strategy: one block per (b,k); block-uniform decode; w float4 hoisted.
// R3 change vs R2: NORMAL stores (nontemporal regressed 48.8->58.3; the
// fill kernel reaches 7 TB/s with normal stores through L2 write-combine).

#define BB   16
#define HH   32
#define WW   32
#define CC   16
#define FF   32
#define KP1  145
#define LL   900            // HO*WO
#define ROW4 (LL * FF / 4)  // float4s per (b,k) row = 7200

typedef float f32x4 __attribute__((ext_vector_type(4)));

__global__ __launch_bounds__(256) void vinput_conv_kernel(
    const float* __restrict__ x,      // (B,H,W,C)
    const float* __restrict__ w,      // (K+1,1,F)
    float* __restrict__ out)          // (B,K+1,HO,WO,F)
{
    const unsigned bid = blockIdx.x;          // 0..2319 = b*145 + k
    const unsigned b   = bid / KP1;
    const unsigned k   = bid - b * KP1;

    const unsigned tid = threadIdx.x;
    const unsigned f4  = tid & 7;             // invariant across the loop (256 % 8 == 0)

    // w float4 for this lane's f-slot: loaded once.
    const f32x4 wv = *reinterpret_cast<const f32x4*>(w + k * FF + f4 * 4);

    f32x4* __restrict__ out4 = reinterpret_cast<f32x4*>(out) + (size_t)bid * ROW4;

    if (k == 144) {
        // bias row: g = 1.0, pure streaming store of the w row
        for (unsigned u = tid; u < ROW4; u += 256) {
            out4[u] = wv;
        }
    } else {
        const unsigned kh = k / 48;           // k = kh*48 + kw*16 + c (block-uniform)
        const unsigned r  = k - kh * 48;
        const unsigned kw = r >> 4;
        const unsigned c  = r & 15;
        const float* __restrict__ xbase =
            x + ((b * HH + kh) * WW + kw) * CC + c;   // + ho*512 + wo*16

        for (unsigned u = tid; u < ROW4; u += 256) {
            const unsigned l  = u >> 3;
            const unsigned ho = l / 30;       // magic-mul
            const unsigned wo = l - ho * 30;
            const float g = xbase[ho * (WW * CC) + wo * CC];
            out4[u] = g * wv;                 // vector-scalar mul, normal store
        }
    }
}

extern "C" void kernel_launch(void* const* d_in, const int* in_sizes, int n_in,
                              void* d_out, int out_size, void* d_ws, size_t ws_size,
                              hipStream_t stream) {
    const float* x = (const float*)d_in[0];   // (16,32,32,16) fp32
    const float* w = (const float*)d_in[1];   // (145,1,32) fp32
    float* out = (float*)d_out;               // (16,145,30,30,32) fp32

    const int grid = BB * KP1;                // 2320 blocks, one per (b,k)
    vinput_conv_kernel<<<grid, 256, 0, stream>>>(x, w, out);
}

// Round 5
// 45.252 us; speedup vs baseline: 1.2886x; 1.0332x over previous
//
#include <hip/hip_runtime.h>

// Problem constants (from reference):
//   B=16, H=32, W=32, C=16, KH=KW=3, F=32, HO=WO=30, K=144 (+1 bias row)
// out[b,k,ho,wo,f]:
//   k < 144: k = kh*48 + kw*16 + c  ->  x[b, ho+kh, wo+kw, c] * w[k,f]
//   k == 144:                            1.0 * w[144,f]
// Output: (16,145,30,30,32) fp32, 267 MB -> write-BW bound (fill rate ~7.1 TB/s).
// R5 change vs R4 (single variable): ho-structured inner loop, 240 active
// lanes (wo=tid>>3, f4=tid&7). Zero divisions in the loop; load/store
// addresses advance by compile-time constants; full unroll -> deep vmem
// pipelining. R4's div-by-30 + index math removed.

#define BB   16
#define HH   32
#define WW   32
#define CC   16
#define FF   32
#define KP1  145
#define LL   900            // HO*WO
#define ROW4 (LL * FF / 4)  // float4s per (b,k) row = 7200

typedef float f32x4 __attribute__((ext_vector_type(4)));

__global__ __launch_bounds__(256) void vinput_conv_kernel(
    const float* __restrict__ x,      // (B,H,W,C)
    const float* __restrict__ w,      // (K+1,1,F)
    float* __restrict__ out)          // (B,K+1,HO,WO,F)
{
    const unsigned bid = blockIdx.x;          // 0..2319 = b*145 + k
    const unsigned b   = bid / KP1;
    const unsigned k   = bid - b * KP1;

    const unsigned tid = threadIdx.x;
    const unsigned f4  = tid & 7;

    // w float4 for this lane's f-slot: loaded once (L2-resident).
    const f32x4 wv = *reinterpret_cast<const f32x4*>(w + k * FF + f4 * 4);

    f32x4* __restrict__ out4 = reinterpret_cast<f32x4*>(out) + (size_t)bid * ROW4;

    if (k == 144) {
        // bias row: pure streaming store of the w row, all 256 lanes
        for (unsigned u = tid; u < ROW4; u += 256) {
            out4[u] = wv;
        }
    } else {
        if (tid >= 240) return;               // 240 lanes = 30 wo x 8 f4
        const unsigned kh = k / 48;           // block-uniform decode, once
        const unsigned r  = k - kh * 48;
        const unsigned kw = r >> 4;
        const unsigned c  = r & 15;
        const unsigned wo = tid >> 3;         // 0..29

        // g address: advances by H-row (W*C floats) per ho iteration
        const float* __restrict__ xp =
            x + ((b * HH + kh) * WW + (kw + wo)) * CC + c;
        // out address: advances by 240 float4s per ho iteration
        f32x4* __restrict__ op = out4 + tid;

        #pragma unroll
        for (int ho = 0; ho < 30; ++ho) {
            const float g = xp[ho * (WW * CC)];
            op[ho * 240] = g * wv;
        }
    }
}

extern "C" void kernel_launch(void* const* d_in, const int* in_sizes, int n_in,
                              void* d_out, int out_size, void* d_ws, size_t ws_size,
                              hipStream_t stream) {
    const float* x = (const float*)d_in[0];   // (16,32,32,16) fp32
    const float* w = (const float*)d_in[1];   // (145,1,32) fp32
    float* out = (float*)d_out;               // (16,145,30,30,32) fp32

    const int grid = BB * KP1;                // 2320 blocks, one per (b,k)
    vinput_conv_kernel<<<grid, 256, 0, stream>>>(x, w, out);
}

// Round 6
// 44.742 us; speedup vs baseline: 1.3033x; 1.0114x over previous
//
#include <hip/hip_runtime.h>

// Problem constants (from reference):
//   B=16, H=32, W=32, C=16, KH=KW=3, F=32, HO=WO=30, K=144 (+1 bias row)
// out[b,k,ho,wo,f]:
//   k < 144: k = kh*48 + kw*16 + c  ->  x[b, ho+kh, wo+kw, c] * w[k,f]
//   k == 144:                            1.0 * w[144,f]
// Output: (16,145,30,30,32) fp32, 267 MB -> write-BW bound (fill ~7.1 TB/s).
// R6 change vs R5 (single variable): work quantum = 1/3 row (10 ho-strips),
// grid 2320 -> 6960. Fixes dynamic-scheduling tail: 2320 blocks = 9.06
// rounds/CU -> 10 rounds (10.3% tail); 6960 = 27.19 -> 28 rounds (3% tail).

#define BB   16
#define HH   32
#define WW   32
#define CC   16
#define FF   32
#define KP1  145
#define LL   900            // HO*WO
#define ROW4 (LL * FF / 4)  // float4s per (b,k) row = 7200
#define SEGS 3              // segments per row
#define SEGHO 10            // ho strips per segment
#define SEG4 (SEGHO * 240)  // float4s per segment = 2400

typedef float f32x4 __attribute__((ext_vector_type(4)));

__global__ __launch_bounds__(256) void vinput_conv_kernel(
    const float* __restrict__ x,      // (B,H,W,C)
    const float* __restrict__ w,      // (K+1,1,F)
    float* __restrict__ out)          // (B,K+1,HO,WO,F)
{
    const unsigned tid = threadIdx.x;
    if (tid >= 240) return;                   // 240 lanes = 30 wo x 8 f4

    const unsigned bid = blockIdx.x;          // 0..6959 = row*3 + seg
    const unsigned row = bid / SEGS;          // 0..2319 = b*145 + k
    const unsigned seg = bid - row * SEGS;    // 0..2
    const unsigned b   = row / KP1;
    const unsigned k   = row - b * KP1;

    const unsigned f4  = tid & 7;
    const unsigned wo  = tid >> 3;            // 0..29

    // w float4 for this lane's f-slot: loaded once (L2-resident).
    const f32x4 wv = *reinterpret_cast<const f32x4*>(w + k * FF + f4 * 4);

    f32x4* __restrict__ op =
        reinterpret_cast<f32x4*>(out) + (size_t)row * ROW4 + seg * SEG4 + tid;

    if (k == 144) {
        // bias row: g = 1.0
        #pragma unroll
        for (int i = 0; i < SEGHO; ++i) {
            op[i * 240] = wv;
        }
    } else {
        const unsigned kh = k / 48;           // k = kh*48 + kw*16 + c (block-uniform)
        const unsigned r  = k - kh * 48;
        const unsigned kw = r >> 4;
        const unsigned c  = r & 15;
        const unsigned ho0 = seg * SEGHO;

        // g address advances by one H-row (W*C = 512 floats) per ho
        const float* __restrict__ xp =
            x + ((b * HH + (kh + ho0)) * WW + (kw + wo)) * CC + c;

        #pragma unroll
        for (int i = 0; i < SEGHO; ++i) {
            const float g = xp[i * (WW * CC)];
            op[i * 240] = g * wv;
        }
    }
}

extern "C" void kernel_launch(void* const* d_in, const int* in_sizes, int n_in,
                              void* d_out, int out_size, void* d_ws, size_t ws_size,
                              hipStream_t stream) {
    const float* x = (const float*)d_in[0];   // (16,32,32,16) fp32
    const float* w = (const float*)d_in[1];   // (145,1,32) fp32
    float* out = (float*)d_out;               // (16,145,30,30,32) fp32

    const int grid = BB * KP1 * SEGS;         // 6960 blocks, 1/3 row each
    vinput_conv_kernel<<<grid, 256, 0, stream>>>(x, w, out);
}